// Round 1
// baseline (2482.802 us; speedup 1.0000x reference)
//
#include <hip/hip_runtime.h>

#define N_NODES 40000
#define N_EDGES 640000
#define NFEAT   128
#define N_GRAPHS 512

// ---------------------------------------------------------------------------
// deg[i] = 1.0 (self loop)
__global__ void init_deg_kernel(float* __restrict__ deg, int n) {
    int i = blockIdx.x * blockDim.x + threadIdx.x;
    if (i < n) deg[i] = 1.0f;
}

// deg[col[e]] += 1
__global__ void edge_deg_kernel(const int* __restrict__ ei, float* __restrict__ deg, int E) {
    int e = blockIdx.x * blockDim.x + threadIdx.x;
    if (e < E) atomicAdd(&deg[ei[E + e]], 1.0f);
}

// dinv = rsqrt(deg)
__global__ void dinv_kernel(const float* __restrict__ deg, float* __restrict__ dinv, int n) {
    int i = blockIdx.x * blockDim.x + threadIdx.x;
    if (i < n) dinv[i] = rsqrtf(deg[i]);
}

// ---------------------------------------------------------------------------
// H[r][c] = sum_k X[r][k] * W[k][c]   (X: [nrows,128], W: [128,128] row-major)
// Block: 256 threads, tile = 32 rows x 128 cols, each thread 4 rows x 4 cols.
// W staged fully in 64 KB LDS (2 blocks/CU -> 8 waves/CU).
__global__ __launch_bounds__(256) void gemm128_kernel(const float* __restrict__ X,
                                                      const float* __restrict__ W,
                                                      float* __restrict__ H,
                                                      int nrows) {
    __shared__ float Ws[128 * 128];
    // stage W: 16384 floats, 256 threads x 16 float4
    for (int i = threadIdx.x * 4; i < 128 * 128; i += 256 * 4) {
        *(float4*)(Ws + i) = *(const float4*)(W + i);
    }
    __syncthreads();

    const int t  = threadIdx.x;
    const int r4 = (t & 7) * 4;    // row group within tile
    const int c4 = (t >> 3) * 4;   // col group

    const int ntiles = nrows / 32; // 40000/32 = 1250, exact
    for (int tile = blockIdx.x; tile < ntiles; tile += gridDim.x) {
        const float* x0 = X + (size_t)(tile * 32 + r4) * NFEAT;
        float acc[4][4] = {};
        #pragma unroll 8
        for (int k = 0; k < 128; k += 4) {
            float4 xv[4];
            float4 wv[4];
            #pragma unroll
            for (int i = 0; i < 4; i++) xv[i] = *(const float4*)(x0 + (size_t)i * NFEAT + k);
            #pragma unroll
            for (int m = 0; m < 4; m++) wv[m] = *(const float4*)(Ws + (k + m) * 128 + c4);
            #pragma unroll
            for (int i = 0; i < 4; i++) {
                const float xi[4] = {xv[i].x, xv[i].y, xv[i].z, xv[i].w};
                #pragma unroll
                for (int m = 0; m < 4; m++) {
                    acc[i][0] += xi[m] * wv[m].x;
                    acc[i][1] += xi[m] * wv[m].y;
                    acc[i][2] += xi[m] * wv[m].z;
                    acc[i][3] += xi[m] * wv[m].w;
                }
            }
        }
        #pragma unroll
        for (int i = 0; i < 4; i++) {
            float4 o = {acc[i][0], acc[i][1], acc[i][2], acc[i][3]};
            *(float4*)(H + (size_t)(tile * 32 + r4 + i) * NFEAT + c4) = o;
        }
    }
}

// ---------------------------------------------------------------------------
// agg[col[e]][:] += H[row[e]][:] * dinv[row]*dinv[col]
// 32 threads per edge, float4 per thread -> 4 atomics.
__global__ __launch_bounds__(256) void edge_scatter_kernel(const int* __restrict__ ei,
                                                           const float* __restrict__ dinv,
                                                           const float* __restrict__ H,
                                                           float* __restrict__ agg,
                                                           int E) {
    long long gid = (long long)blockIdx.x * blockDim.x + threadIdx.x;
    int e = (int)(gid >> 5);
    if (e >= E) return;
    int c4 = ((int)gid & 31) * 4;
    int r = ei[e];
    int c = ei[E + e];
    float norm = dinv[r] * dinv[c];
    const float4 hv = *(const float4*)(H + (size_t)r * NFEAT + c4);
    float* dst = agg + (size_t)c * NFEAT + c4;
    atomicAdd(dst + 0, hv.x * norm);
    atomicAdd(dst + 1, hv.y * norm);
    atomicAdd(dst + 2, hv.z * norm);
    atomicAdd(dst + 3, hv.w * norm);
}

// ---------------------------------------------------------------------------
// agg = relu(agg + H*dinv^2 + b)   (in place)
__global__ void post_kernel(float* __restrict__ agg, const float* __restrict__ H,
                            const float* __restrict__ dinv, const float* __restrict__ b,
                            int n) {
    int gid = blockIdx.x * blockDim.x + threadIdx.x;
    if (gid >= n * 32) return;
    int node = gid >> 5;
    int c4 = (gid & 31) * 4;
    float di = dinv[node];
    float s = di * di;
    float4 a  = *(float4*)(agg + (size_t)gid * 4);
    float4 hv = *(const float4*)(H + (size_t)gid * 4);
    float4 bb = *(const float4*)(b + c4);
    float4 o;
    o.x = fmaxf(a.x + hv.x * s + bb.x, 0.0f);
    o.y = fmaxf(a.y + hv.y * s + bb.y, 0.0f);
    o.z = fmaxf(a.z + hv.z * s + bb.z, 0.0f);
    o.w = fmaxf(a.w + hv.w * s + bb.w, 0.0f);
    *(float4*)(agg + (size_t)gid * 4) = o;
}

// ---------------------------------------------------------------------------
// out[g] = mean_{n in graph g}(H[n]) . Wfc + bfc      (batch sorted -> bsearch)
__global__ __launch_bounds__(128) void pool_fc_kernel(const float* __restrict__ H,
                                                      const int* __restrict__ batch,
                                                      const float* __restrict__ Wfc,
                                                      const float* __restrict__ bfc,
                                                      float* __restrict__ out, int n) {
    int g = blockIdx.x;
    int tid = threadIdx.x;
    // lower_bound(batch, g)
    int lo = 0, hi = n;
    while (lo < hi) { int mid = (lo + hi) >> 1; if (batch[mid] < g) lo = mid + 1; else hi = mid; }
    int start = lo;
    hi = n;
    while (lo < hi) { int mid = (lo + hi) >> 1; if (batch[mid] < g + 1) lo = mid + 1; else hi = mid; }
    int end = lo;

    float acc = 0.0f;
    for (int nd = start; nd < end; ++nd) acc += H[(size_t)nd * NFEAT + tid];
    float cnt = (float)((end - start) > 0 ? (end - start) : 1);
    float v = (acc / cnt) * Wfc[tid];

    __shared__ float red[128];
    red[tid] = v;
    __syncthreads();
    #pragma unroll
    for (int s = 64; s > 0; s >>= 1) {
        if (tid < s) red[tid] += red[tid + s];
        __syncthreads();
    }
    if (tid == 0) out[g] = red[0] + bfc[0];
}

// ---------------------------------------------------------------------------
extern "C" void kernel_launch(void* const* d_in, const int* in_sizes, int n_in,
                              void* d_out, int out_size, void* d_ws, size_t ws_size,
                              hipStream_t stream) {
    const float* x     = (const float*)d_in[0];
    const int*   ei    = (const int*)  d_in[1];
    const int*   batch = (const int*)  d_in[2];
    const float* W1    = (const float*)d_in[3];
    const float* b1    = (const float*)d_in[4];
    const float* W2    = (const float*)d_in[5];
    const float* b2    = (const float*)d_in[6];
    const float* Wfc   = (const float*)d_in[7];
    const float* bfc   = (const float*)d_in[8];
    float* out = (float*)d_out;

    float* ws   = (float*)d_ws;
    float* deg  = ws;                                   // N
    float* dinv = ws + N_NODES;                         // N
    float* hbuf = ws + 2 * N_NODES;                     // N*128
    float* agg  = hbuf + (size_t)N_NODES * NFEAT;       // N*128

    const size_t feat_bytes = (size_t)N_NODES * NFEAT * sizeof(float);

    // degrees / norms (shared by both layers)
    init_deg_kernel<<<(N_NODES + 255) / 256, 256, 0, stream>>>(deg, N_NODES);
    edge_deg_kernel<<<(N_EDGES + 255) / 256, 256, 0, stream>>>(ei, deg, N_EDGES);
    dinv_kernel<<<(N_NODES + 255) / 256, 256, 0, stream>>>(deg, dinv, N_NODES);

    // ---- layer 1 ----
    hipMemsetAsync(agg, 0, feat_bytes, stream);
    gemm128_kernel<<<512, 256, 0, stream>>>(x, W1, hbuf, N_NODES);
    edge_scatter_kernel<<<(N_EDGES * 32) / 256, 256, 0, stream>>>(ei, dinv, hbuf, agg, N_EDGES);
    post_kernel<<<(N_NODES * 32) / 256, 256, 0, stream>>>(agg, hbuf, dinv, b1, N_NODES);

    // ---- layer 2 ----  (gemm reads agg, then agg is recycled as accumulator)
    gemm128_kernel<<<512, 256, 0, stream>>>(agg, W2, hbuf, N_NODES);
    hipMemsetAsync(agg, 0, feat_bytes, stream);
    edge_scatter_kernel<<<(N_EDGES * 32) / 256, 256, 0, stream>>>(ei, dinv, hbuf, agg, N_EDGES);
    post_kernel<<<(N_NODES * 32) / 256, 256, 0, stream>>>(agg, hbuf, dinv, b2, N_NODES);

    // ---- pool + fc ----
    pool_fc_kernel<<<N_GRAPHS, 128, 0, stream>>>(agg, batch, Wfc, bfc, out, N_NODES);
}

// Round 2
// 461.939 us; speedup vs baseline: 5.3747x; 5.3747x over previous
//
#include <hip/hip_runtime.h>

#define N_NODES 40000
#define N_EDGES 640000
#define NFEAT   128
#define N_GRAPHS 512
#define SCAN_NB 157   // ceil(40000/256)

// ===========================================================================
// Common small kernels
// ===========================================================================

// int in-degree histogram: degcnt[col[e]] += 1
__global__ void edge_deg_int_kernel(const int* __restrict__ ei, int* __restrict__ degcnt, int E) {
    int e = blockIdx.x * blockDim.x + threadIdx.x;
    if (e < E) atomicAdd(&degcnt[ei[E + e]], 1);
}

// dinv = rsqrt(1 + degcnt)
__global__ void dinv_from_int_kernel(const int* __restrict__ degcnt, float* __restrict__ dinv, int n) {
    int i = blockIdx.x * blockDim.x + threadIdx.x;
    if (i < n) dinv[i] = rsqrtf(1.0f + (float)degcnt[i]);
}

// ---- hierarchical exclusive scan over degcnt -> rowptr ----
__global__ void scan1_kernel(const int* __restrict__ in, int* __restrict__ out,
                             int* __restrict__ bsums, int n) {
    __shared__ int tmp[256];
    int t = threadIdx.x;
    int i = blockIdx.x * 256 + t;
    int v = (i < n) ? in[i] : 0;
    tmp[t] = v;
    __syncthreads();
    for (int off = 1; off < 256; off <<= 1) {
        int add = (t >= off) ? tmp[t - off] : 0;
        __syncthreads();
        tmp[t] += add;
        __syncthreads();
    }
    if (i < n) out[i] = tmp[t] - v;          // exclusive within block
    if (t == 255) bsums[blockIdx.x] = tmp[255];
}

__global__ void scan2_kernel(int* __restrict__ bsums, int nb) {
    __shared__ int tmp[256];
    int t = threadIdx.x;
    int v = (t < nb) ? bsums[t] : 0;
    tmp[t] = v;
    __syncthreads();
    for (int off = 1; off < 256; off <<= 1) {
        int add = (t >= off) ? tmp[t - off] : 0;
        __syncthreads();
        tmp[t] += add;
        __syncthreads();
    }
    if (t < nb) bsums[t] = tmp[t] - v;       // exclusive
}

// rowptr[i] += bsums[blk]; cursor[i] = rowptr[i]; rowptr[n] = E
__global__ void scan3_kernel(int* __restrict__ rowptr, const int* __restrict__ bsums,
                             int* __restrict__ cursor, int n, int E) {
    int i = blockIdx.x * 256 + threadIdx.x;
    if (i < n) {
        int v = rowptr[i] + bsums[blockIdx.x];
        rowptr[i] = v;
        cursor[i] = v;
    }
    if (i == 0) rowptr[n] = E;
}

// csr[atomic cursor[col]] = row
template <typename IdxT>
__global__ void fill_kernel(const int* __restrict__ ei, int* __restrict__ cursor,
                            IdxT* __restrict__ csr, int E) {
    int e = blockIdx.x * blockDim.x + threadIdx.x;
    if (e < E) {
        int c = ei[E + e];
        int p = atomicAdd(&cursor[c], 1);
        csr[p] = (IdxT)ei[e];
    }
}

// ===========================================================================
// GEMM: Ht[r][c] = dinv[r] * sum_k X[r][k] * W[k][c]
// Block 256 threads, tile 32 rows x 128 cols, thread = 4x4. W in LDS.
// ===========================================================================
__global__ __launch_bounds__(256) void gemm128_kernel(const float* __restrict__ X,
                                                      const float* __restrict__ W,
                                                      const float* __restrict__ dinv,
                                                      float* __restrict__ H,
                                                      int nrows) {
    __shared__ float Ws[128 * 128];
    for (int i = threadIdx.x * 4; i < 128 * 128; i += 256 * 4) {
        *(float4*)(Ws + i) = *(const float4*)(W + i);
    }
    __syncthreads();

    const int t  = threadIdx.x;
    const int r4 = (t & 7) * 4;
    const int c4 = (t >> 3) * 4;

    const int ntiles = nrows / 32;
    for (int tile = blockIdx.x; tile < ntiles; tile += gridDim.x) {
        const float* x0 = X + (size_t)(tile * 32 + r4) * NFEAT;
        float acc[4][4] = {};
        #pragma unroll 8
        for (int k = 0; k < 128; k += 4) {
            float4 xv[4];
            float4 wv[4];
            #pragma unroll
            for (int i = 0; i < 4; i++) xv[i] = *(const float4*)(x0 + (size_t)i * NFEAT + k);
            #pragma unroll
            for (int m = 0; m < 4; m++) wv[m] = *(const float4*)(Ws + (k + m) * 128 + c4);
            #pragma unroll
            for (int i = 0; i < 4; i++) {
                const float xi[4] = {xv[i].x, xv[i].y, xv[i].z, xv[i].w};
                #pragma unroll
                for (int m = 0; m < 4; m++) {
                    acc[i][0] += xi[m] * wv[m].x;
                    acc[i][1] += xi[m] * wv[m].y;
                    acc[i][2] += xi[m] * wv[m].z;
                    acc[i][3] += xi[m] * wv[m].w;
                }
            }
        }
        #pragma unroll
        for (int i = 0; i < 4; i++) {
            float dr = dinv[tile * 32 + r4 + i];
            float4 o = {acc[i][0] * dr, acc[i][1] * dr, acc[i][2] * dr, acc[i][3] * dr};
            *(float4*)(H + (size_t)(tile * 32 + r4 + i) * NFEAT + c4) = o;
        }
    }
}

// ===========================================================================
// Gather (CSR): out[c] = relu(dinv[c]*(sum_{r in N(c)} Ht[r] + Ht[c]) + b)
// One wave (64 lanes) per node, float2 per lane -> 512 B per neighbor row.
// ===========================================================================
template <typename IdxT>
__global__ __launch_bounds__(256) void gather_kernel(const int* __restrict__ rowptr,
                                                     const IdxT* __restrict__ csr,
                                                     const float* __restrict__ dinv,
                                                     const float* __restrict__ Ht,
                                                     const float* __restrict__ bias,
                                                     float* __restrict__ out, int n) {
    int gid = blockIdx.x * blockDim.x + threadIdx.x;
    int node = gid >> 6;
    int lane = gid & 63;
    if (node >= n) return;
    int start = rowptr[node];
    int end   = rowptr[node + 1];
    const int f2 = lane * 2;

    // self-loop term
    float2 acc0 = *(const float2*)(Ht + (size_t)node * NFEAT + f2);
    float2 acc1 = {0.0f, 0.0f};

    int j = start;
    for (; j + 1 < end; j += 2) {
        int r0 = (int)csr[j];
        int r1 = (int)csr[j + 1];
        float2 v0 = *(const float2*)(Ht + (size_t)r0 * NFEAT + f2);
        float2 v1 = *(const float2*)(Ht + (size_t)r1 * NFEAT + f2);
        acc0.x += v0.x; acc0.y += v0.y;
        acc1.x += v1.x; acc1.y += v1.y;
    }
    if (j < end) {
        int r0 = (int)csr[j];
        float2 v0 = *(const float2*)(Ht + (size_t)r0 * NFEAT + f2);
        acc0.x += v0.x; acc0.y += v0.y;
    }
    acc0.x += acc1.x; acc0.y += acc1.y;

    float di = dinv[node];
    float2 bb = *(const float2*)(bias + f2);
    float2 o;
    o.x = fmaxf(acc0.x * di + bb.x, 0.0f);
    o.y = fmaxf(acc0.y * di + bb.y, 0.0f);
    *(float2*)(out + (size_t)node * NFEAT + f2) = o;
}

// ===========================================================================
// Fallback (tier C) atomic scatter path — round-1 kernels adapted to scaled Ht
// msg(r->c) = dinv[c]*Ht[r] ;  self-loop = dinv[c]*Ht[c]
// ===========================================================================
__global__ __launch_bounds__(256) void edge_scatter_kernel(const int* __restrict__ ei,
                                                           const float* __restrict__ dinv,
                                                           const float* __restrict__ H,
                                                           float* __restrict__ agg,
                                                           int E) {
    long long gid = (long long)blockIdx.x * blockDim.x + threadIdx.x;
    int e = (int)(gid >> 5);
    if (e >= E) return;
    int c4 = ((int)gid & 31) * 4;
    int r = ei[e];
    int c = ei[E + e];
    float norm = dinv[c];
    const float4 hv = *(const float4*)(H + (size_t)r * NFEAT + c4);
    float* dst = agg + (size_t)c * NFEAT + c4;
    atomicAdd(dst + 0, hv.x * norm);
    atomicAdd(dst + 1, hv.y * norm);
    atomicAdd(dst + 2, hv.z * norm);
    atomicAdd(dst + 3, hv.w * norm);
}

__global__ void post_kernel(float* __restrict__ agg, const float* __restrict__ H,
                            const float* __restrict__ dinv, const float* __restrict__ b,
                            int n) {
    int gid = blockIdx.x * blockDim.x + threadIdx.x;
    if (gid >= n * 32) return;
    int node = gid >> 5;
    int c4 = (gid & 31) * 4;
    float s = dinv[node];
    float4 a  = *(float4*)(agg + (size_t)gid * 4);
    float4 hv = *(const float4*)(H + (size_t)gid * 4);
    float4 bb = *(const float4*)(b + c4);
    float4 o;
    o.x = fmaxf(a.x + hv.x * s + bb.x, 0.0f);
    o.y = fmaxf(a.y + hv.y * s + bb.y, 0.0f);
    o.z = fmaxf(a.z + hv.z * s + bb.z, 0.0f);
    o.w = fmaxf(a.w + hv.w * s + bb.w, 0.0f);
    *(float4*)(agg + (size_t)gid * 4) = o;
}

// ===========================================================================
// Pool + FC: out[g] = mean_{n in g}(A2[n]) . Wfc + bfc
// ===========================================================================
__global__ __launch_bounds__(128) void pool_fc_kernel(const float* __restrict__ H,
                                                      const int* __restrict__ batch,
                                                      const float* __restrict__ Wfc,
                                                      const float* __restrict__ bfc,
                                                      float* __restrict__ out, int n) {
    int g = blockIdx.x;
    int tid = threadIdx.x;
    int lo = 0, hi = n;
    while (lo < hi) { int mid = (lo + hi) >> 1; if (batch[mid] < g) lo = mid + 1; else hi = mid; }
    int start = lo;
    hi = n;
    while (lo < hi) { int mid = (lo + hi) >> 1; if (batch[mid] < g + 1) lo = mid + 1; else hi = mid; }
    int end = lo;

    float acc = 0.0f;
    for (int nd = start; nd < end; ++nd) acc += H[(size_t)nd * NFEAT + tid];
    float cnt = (float)((end - start) > 0 ? (end - start) : 1);
    float v = (acc / cnt) * Wfc[tid];

    __shared__ float red[128];
    red[tid] = v;
    __syncthreads();
    #pragma unroll
    for (int s = 64; s > 0; s >>= 1) {
        if (tid < s) red[tid] += red[tid + s];
        __syncthreads();
    }
    if (tid == 0) out[g] = red[0] + bfc[0];
}

// ===========================================================================
// Host launcher
// ===========================================================================
template <typename IdxT>
static void run_csr_path(const float* x, const int* ei, const int* batch,
                         const float* W1, const float* b1, const float* W2,
                         const float* b2, const float* Wfc, const float* bfc,
                         float* out, void* d_ws, hipStream_t stream) {
    char* ws = (char*)d_ws;
    const size_t fbytes = (size_t)N_NODES * NFEAT * sizeof(float);
    float* hbuf   = (float*)ws;                                // 20.48 MB
    float* obuf   = (float*)(ws + fbytes);                     // 20.48 MB
    IdxT*  csr    = (IdxT*)(ws + 2 * fbytes);                  // E * sizeof(IdxT)
    char*  p      = ws + 2 * fbytes + ((size_t)N_EDGES * sizeof(IdxT) + 15) / 16 * 16;
    int*   rowptr = (int*)p;                                   // N+1 ints
    float* dinv   = (float*)(p + ((size_t)(N_NODES + 1) * 4 + 15) / 16 * 16);  // N floats

    // scratch overlapping obuf (dead until gather1 writes it)
    int* degcnt = (int*)obuf;                 // N ints
    int* cursor = (int*)obuf + N_NODES;       // N ints
    int* bsums  = (int*)obuf + 2 * N_NODES;   // SCAN_NB ints

    // ---- CSR build ----
    hipMemsetAsync(degcnt, 0, (size_t)N_NODES * sizeof(int), stream);
    edge_deg_int_kernel<<<N_EDGES / 256, 256, 0, stream>>>(ei, degcnt, N_EDGES);
    dinv_from_int_kernel<<<SCAN_NB, 256, 0, stream>>>(degcnt, dinv, N_NODES);
    scan1_kernel<<<SCAN_NB, 256, 0, stream>>>(degcnt, rowptr, bsums, N_NODES);
    scan2_kernel<<<1, 256, 0, stream>>>(bsums, SCAN_NB);
    scan3_kernel<<<SCAN_NB, 256, 0, stream>>>(rowptr, bsums, cursor, N_NODES, N_EDGES);
    fill_kernel<IdxT><<<N_EDGES / 256, 256, 0, stream>>>(ei, cursor, csr, N_EDGES);

    // ---- layer 1 ----
    gemm128_kernel<<<512, 256, 0, stream>>>(x, W1, dinv, hbuf, N_NODES);
    gather_kernel<IdxT><<<(N_NODES * 64) / 256, 256, 0, stream>>>(rowptr, csr, dinv, hbuf, b1, obuf, N_NODES);

    // ---- layer 2 ----
    gemm128_kernel<<<512, 256, 0, stream>>>(obuf, W2, dinv, hbuf, N_NODES);
    gather_kernel<IdxT><<<(N_NODES * 64) / 256, 256, 0, stream>>>(rowptr, csr, dinv, hbuf, b2, obuf, N_NODES);

    // ---- pool + fc ----
    pool_fc_kernel<<<N_GRAPHS, 128, 0, stream>>>(obuf, batch, Wfc, bfc, out, N_NODES);
}

extern "C" void kernel_launch(void* const* d_in, const int* in_sizes, int n_in,
                              void* d_out, int out_size, void* d_ws, size_t ws_size,
                              hipStream_t stream) {
    const float* x     = (const float*)d_in[0];
    const int*   ei    = (const int*)  d_in[1];
    const int*   batch = (const int*)  d_in[2];
    const float* W1    = (const float*)d_in[3];
    const float* b1    = (const float*)d_in[4];
    const float* W2    = (const float*)d_in[5];
    const float* b2    = (const float*)d_in[6];
    const float* Wfc   = (const float*)d_in[7];
    const float* bfc   = (const float*)d_in[8];
    float* out = (float*)d_out;

    const size_t fbytes = (size_t)N_NODES * NFEAT * sizeof(float);
    const size_t needA = 2 * fbytes + ((size_t)N_EDGES * 4 + 15) / 16 * 16
                       + ((size_t)(N_NODES + 1) * 4 + 15) / 16 * 16
                       + (size_t)N_NODES * 4;
    const size_t needB = 2 * fbytes + ((size_t)N_EDGES * 2 + 15) / 16 * 16
                       + ((size_t)(N_NODES + 1) * 4 + 15) / 16 * 16
                       + (size_t)N_NODES * 4;

    if (ws_size >= needA) {
        run_csr_path<int>(x, ei, batch, W1, b1, W2, b2, Wfc, bfc, out, d_ws, stream);
    } else if (ws_size >= needB) {
        run_csr_path<unsigned short>(x, ei, batch, W1, b1, W2, b2, Wfc, bfc, out, d_ws, stream);
    } else {
        // Tier C: round-1 atomic-scatter fallback (fits in 41.3 MB)
        float* ws   = (float*)d_ws;
        int*   degc = (int*)ws;                              // N (int histogram)
        float* dinv = ws + N_NODES;                          // N
        float* hbuf = ws + 2 * N_NODES;                      // N*128
        float* agg  = hbuf + (size_t)N_NODES * NFEAT;        // N*128

        hipMemsetAsync(degc, 0, (size_t)N_NODES * sizeof(int), stream);
        edge_deg_int_kernel<<<N_EDGES / 256, 256, 0, stream>>>(ei, degc, N_EDGES);
        dinv_from_int_kernel<<<SCAN_NB, 256, 0, stream>>>(degc, dinv, N_NODES);

        hipMemsetAsync(agg, 0, fbytes, stream);
        gemm128_kernel<<<512, 256, 0, stream>>>(x, W1, dinv, hbuf, N_NODES);
        edge_scatter_kernel<<<(N_EDGES * 32) / 256, 256, 0, stream>>>(ei, dinv, hbuf, agg, N_EDGES);
        post_kernel<<<(N_NODES * 32) / 256, 256, 0, stream>>>(agg, hbuf, dinv, b1, N_NODES);

        gemm128_kernel<<<512, 256, 0, stream>>>(agg, W2, dinv, hbuf, N_NODES);
        hipMemsetAsync(agg, 0, fbytes, stream);
        edge_scatter_kernel<<<(N_EDGES * 32) / 256, 256, 0, stream>>>(ei, dinv, hbuf, agg, N_EDGES);
        post_kernel<<<(N_NODES * 32) / 256, 256, 0, stream>>>(agg, hbuf, dinv, b2, N_NODES);

        pool_fc_kernel<<<N_GRAPHS, 128, 0, stream>>>(agg, batch, Wfc, bfc, out, N_NODES);
    }
}

// Round 3
// 329.939 us; speedup vs baseline: 7.5250x; 1.4001x over previous
//
#include <hip/hip_runtime.h>

#define N_NODES 40000
#define N_EDGES 640000
#define NFEAT   128
#define N_GRAPHS 512
#define SCAN_NB 157   // ceil(40000/256)

// ===========================================================================
// CSR build kernels
// ===========================================================================

__global__ void edge_deg_int_kernel(const int* __restrict__ ei, int* __restrict__ degcnt, int E) {
    int e = blockIdx.x * blockDim.x + threadIdx.x;
    if (e < E) atomicAdd(&degcnt[ei[E + e]], 1);
}

// kept for tier C
__global__ void dinv_from_int_kernel(const int* __restrict__ degcnt, float* __restrict__ dinv, int n) {
    int i = blockIdx.x * blockDim.x + threadIdx.x;
    if (i < n) dinv[i] = rsqrtf(1.0f + (float)degcnt[i]);
}

// block-local exclusive scan + per-block sums + fused dinv = rsqrt(1+deg)
__global__ void scan1_kernel(const int* __restrict__ in, int* __restrict__ out,
                             int* __restrict__ bsums, float* __restrict__ dinv, int n) {
    __shared__ int tmp[256];
    int t = threadIdx.x;
    int i = blockIdx.x * 256 + t;
    int v = (i < n) ? in[i] : 0;
    if (i < n) dinv[i] = rsqrtf(1.0f + (float)v);
    tmp[t] = v;
    __syncthreads();
    for (int off = 1; off < 256; off <<= 1) {
        int add = (t >= off) ? tmp[t - off] : 0;
        __syncthreads();
        tmp[t] += add;
        __syncthreads();
    }
    if (i < n) out[i] = tmp[t] - v;
    if (t == 255) bsums[blockIdx.x] = tmp[255];
}

__global__ void scan2_kernel(int* __restrict__ bsums, int nb) {
    __shared__ int tmp[256];
    int t = threadIdx.x;
    int v = (t < nb) ? bsums[t] : 0;
    tmp[t] = v;
    __syncthreads();
    for (int off = 1; off < 256; off <<= 1) {
        int add = (t >= off) ? tmp[t - off] : 0;
        __syncthreads();
        tmp[t] += add;
        __syncthreads();
    }
    if (t < nb) bsums[t] = tmp[t] - v;
}

__global__ void scan3_kernel(int* __restrict__ rowptr, const int* __restrict__ bsums,
                             int* __restrict__ cursor, int n, int E) {
    int i = blockIdx.x * 256 + threadIdx.x;
    if (i < n) {
        int v = rowptr[i] + bsums[blockIdx.x];
        rowptr[i] = v;
        cursor[i] = v;
    }
    if (i == 0) rowptr[n] = E;
}

template <typename IdxT>
__global__ void fill_kernel(const int* __restrict__ ei, int* __restrict__ cursor,
                            IdxT* __restrict__ csr, int E) {
    int e = blockIdx.x * blockDim.x + threadIdx.x;
    if (e < E) {
        int c = ei[E + e];
        int p = atomicAdd(&cursor[c], 1);
        csr[p] = (IdxT)ei[e];
    }
}

// ===========================================================================
// GEMM v2: Ht[r][c] = dinv[r] * sum_k X[r][k] * W[k][c]
// Block = 256 threads computes 64 rows x 64 cols; W col-half (128x64=32KB) in
// LDS -> 4 blocks/CU (16 waves/CU vs 8 in v1). Explicit X prefetch (double
// buffer) so the k-chunk waitcnt doesn't drain the next chunk's loads.
// Grid: (nrows/64)*2, blockIdx.x = tile*2 + colhalf.
// ===========================================================================
__global__ __launch_bounds__(256, 4) void gemm64_kernel(const float* __restrict__ X,
                                                        const float* __restrict__ W,
                                                        const float* __restrict__ dinv,
                                                        float* __restrict__ H) {
    __shared__ float Ws[128 * 64];
    const int colhalf = blockIdx.x & 1;
    const int tile    = blockIdx.x >> 1;

    // stage W half: 8192 floats = 2048 float4, 256 threads x 8
    for (int i = threadIdx.x; i < 2048; i += 256) {
        int k   = i >> 4;
        int cc4 = (i & 15) * 4;
        *(float4*)(Ws + k * 64 + cc4) = *(const float4*)(W + k * 128 + colhalf * 64 + cc4);
    }
    __syncthreads();

    const int rg = threadIdx.x >> 4;   // 0..15 row group
    const int cg = threadIdx.x & 15;   // 0..15 col group
    const int row0 = tile * 64 + rg * 4;
    const float* x0 = X + (size_t)row0 * NFEAT;

    float acc[4][4] = {};
    float4 xc[4], xn[4];
    #pragma unroll
    for (int i = 0; i < 4; i++) xc[i] = *(const float4*)(x0 + (size_t)i * NFEAT);

    #pragma unroll 4
    for (int k = 0; k < 128; k += 4) {
        // prefetch next chunk (wraps to 0 on last iter; harmless L1 hit)
        const int kn = (k + 4) & 127;
        #pragma unroll
        for (int i = 0; i < 4; i++) xn[i] = *(const float4*)(x0 + (size_t)i * NFEAT + kn);

        float4 wv[4];
        #pragma unroll
        for (int m = 0; m < 4; m++) wv[m] = *(const float4*)(Ws + (k + m) * 64 + cg * 4);

        #pragma unroll
        for (int i = 0; i < 4; i++) {
            const float xi[4] = {xc[i].x, xc[i].y, xc[i].z, xc[i].w};
            #pragma unroll
            for (int m = 0; m < 4; m++) {
                acc[i][0] += xi[m] * wv[m].x;
                acc[i][1] += xi[m] * wv[m].y;
                acc[i][2] += xi[m] * wv[m].z;
                acc[i][3] += xi[m] * wv[m].w;
            }
        }
        #pragma unroll
        for (int i = 0; i < 4; i++) xc[i] = xn[i];
    }

    #pragma unroll
    for (int i = 0; i < 4; i++) {
        float dr = dinv[row0 + i];
        float4 o = {acc[i][0] * dr, acc[i][1] * dr, acc[i][2] * dr, acc[i][3] * dr};
        *(float4*)(H + (size_t)(row0 + i) * NFEAT + colhalf * 64 + cg * 4) = o;
    }
}

// ===========================================================================
// Gather v2 (CSR): out[c] = relu(dinv[c]*(sum_{r in N(c)} Ht[r] + Ht[c]) + b)
// One wave per node. Lane covers float4 (32 lanes span a 512B row); the two
// half-waves take alternating neighbors -> one dwordx4 instr covers 2 rows
// (1 KB). Cross-half combine via shfl_xor(32).
// ===========================================================================
template <typename IdxT>
__global__ __launch_bounds__(256) void gather4_kernel(const int* __restrict__ rowptr,
                                                      const IdxT* __restrict__ csr,
                                                      const float* __restrict__ dinv,
                                                      const float* __restrict__ Ht,
                                                      const float* __restrict__ bias,
                                                      float* __restrict__ out, int n) {
    int gid  = blockIdx.x * blockDim.x + threadIdx.x;
    int node = gid >> 6;
    if (node >= n) return;
    int lane = threadIdx.x & 63;
    int half = lane >> 5;
    int f4   = (lane & 31) * 4;

    int start = rowptr[node];
    int end   = rowptr[node + 1];

    float4 a0 = {0.f, 0.f, 0.f, 0.f};
    float4 a1 = {0.f, 0.f, 0.f, 0.f};
    if (half == 0) a0 = *(const float4*)(Ht + (size_t)node * NFEAT + f4);  // self loop

    int j = start + half;
    for (; j + 2 < end; j += 4) {
        int r0 = (int)csr[j];
        int r1 = (int)csr[j + 2];
        float4 v0 = *(const float4*)(Ht + (size_t)r0 * NFEAT + f4);
        float4 v1 = *(const float4*)(Ht + (size_t)r1 * NFEAT + f4);
        a0.x += v0.x; a0.y += v0.y; a0.z += v0.z; a0.w += v0.w;
        a1.x += v1.x; a1.y += v1.y; a1.z += v1.z; a1.w += v1.w;
    }
    if (j < end) {
        int r0 = (int)csr[j];
        float4 v0 = *(const float4*)(Ht + (size_t)r0 * NFEAT + f4);
        a0.x += v0.x; a0.y += v0.y; a0.z += v0.z; a0.w += v0.w;
    }
    a0.x += a1.x; a0.y += a1.y; a0.z += a1.z; a0.w += a1.w;

    // combine halves
    a0.x += __shfl_xor(a0.x, 32, 64);
    a0.y += __shfl_xor(a0.y, 32, 64);
    a0.z += __shfl_xor(a0.z, 32, 64);
    a0.w += __shfl_xor(a0.w, 32, 64);

    if (half == 0) {
        float di  = dinv[node];
        float4 bb = *(const float4*)(bias + f4);
        float4 o;
        o.x = fmaxf(a0.x * di + bb.x, 0.0f);
        o.y = fmaxf(a0.y * di + bb.y, 0.0f);
        o.z = fmaxf(a0.z * di + bb.z, 0.0f);
        o.w = fmaxf(a0.w * di + bb.w, 0.0f);
        *(float4*)(out + (size_t)node * NFEAT + f4) = o;
    }
}

// ===========================================================================
// Tier C fallback: atomic scatter (Ht pre-scaled by dinv[r])
// ===========================================================================
__global__ __launch_bounds__(256) void edge_scatter_kernel(const int* __restrict__ ei,
                                                           const float* __restrict__ dinv,
                                                           const float* __restrict__ H,
                                                           float* __restrict__ agg,
                                                           int E) {
    long long gid = (long long)blockIdx.x * blockDim.x + threadIdx.x;
    int e = (int)(gid >> 5);
    if (e >= E) return;
    int c4 = ((int)gid & 31) * 4;
    int r = ei[e];
    int c = ei[E + e];
    float norm = dinv[c];
    const float4 hv = *(const float4*)(H + (size_t)r * NFEAT + c4);
    float* dst = agg + (size_t)c * NFEAT + c4;
    atomicAdd(dst + 0, hv.x * norm);
    atomicAdd(dst + 1, hv.y * norm);
    atomicAdd(dst + 2, hv.z * norm);
    atomicAdd(dst + 3, hv.w * norm);
}

__global__ void post_kernel(float* __restrict__ agg, const float* __restrict__ H,
                            const float* __restrict__ dinv, const float* __restrict__ b,
                            int n) {
    int gid = blockIdx.x * blockDim.x + threadIdx.x;
    if (gid >= n * 32) return;
    int node = gid >> 5;
    int c4 = (gid & 31) * 4;
    float s = dinv[node];
    float4 a  = *(float4*)(agg + (size_t)gid * 4);
    float4 hv = *(const float4*)(H + (size_t)gid * 4);
    float4 bb = *(const float4*)(b + c4);
    float4 o;
    o.x = fmaxf(a.x + hv.x * s + bb.x, 0.0f);
    o.y = fmaxf(a.y + hv.y * s + bb.y, 0.0f);
    o.z = fmaxf(a.z + hv.z * s + bb.z, 0.0f);
    o.w = fmaxf(a.w + hv.w * s + bb.w, 0.0f);
    *(float4*)(agg + (size_t)gid * 4) = o;
}

// ===========================================================================
// Pool + FC
// ===========================================================================
__global__ __launch_bounds__(128) void pool_fc_kernel(const float* __restrict__ H,
                                                      const int* __restrict__ batch,
                                                      const float* __restrict__ Wfc,
                                                      const float* __restrict__ bfc,
                                                      float* __restrict__ out, int n) {
    int g = blockIdx.x;
    int tid = threadIdx.x;
    int lo = 0, hi = n;
    while (lo < hi) { int mid = (lo + hi) >> 1; if (batch[mid] < g) lo = mid + 1; else hi = mid; }
    int start = lo;
    hi = n;
    while (lo < hi) { int mid = (lo + hi) >> 1; if (batch[mid] < g + 1) lo = mid + 1; else hi = mid; }
    int end = lo;

    float acc = 0.0f;
    for (int nd = start; nd < end; ++nd) acc += H[(size_t)nd * NFEAT + tid];
    float cnt = (float)((end - start) > 0 ? (end - start) : 1);
    float v = (acc / cnt) * Wfc[tid];

    __shared__ float red[128];
    red[tid] = v;
    __syncthreads();
    #pragma unroll
    for (int s = 64; s > 0; s >>= 1) {
        if (tid < s) red[tid] += red[tid + s];
        __syncthreads();
    }
    if (tid == 0) out[g] = red[0] + bfc[0];
}

// ===========================================================================
// Host launcher
// ===========================================================================
template <typename IdxT>
static void run_csr_path(const float* x, const int* ei, const int* batch,
                         const float* W1, const float* b1, const float* W2,
                         const float* b2, const float* Wfc, const float* bfc,
                         float* out, void* d_ws, hipStream_t stream) {
    char* ws = (char*)d_ws;
    const size_t fbytes = (size_t)N_NODES * NFEAT * sizeof(float);
    float* hbuf   = (float*)ws;
    float* obuf   = (float*)(ws + fbytes);
    IdxT*  csr    = (IdxT*)(ws + 2 * fbytes);
    char*  p      = ws + 2 * fbytes + ((size_t)N_EDGES * sizeof(IdxT) + 15) / 16 * 16;
    int*   rowptr = (int*)p;
    float* dinv   = (float*)(p + ((size_t)(N_NODES + 1) * 4 + 15) / 16 * 16);

    // scratch overlapping obuf (dead until gather1 writes it)
    int* degcnt = (int*)obuf;
    int* cursor = (int*)obuf + N_NODES;
    int* bsums  = (int*)obuf + 2 * N_NODES;

    // ---- CSR build + norms ----
    hipMemsetAsync(degcnt, 0, (size_t)N_NODES * sizeof(int), stream);
    edge_deg_int_kernel<<<N_EDGES / 256, 256, 0, stream>>>(ei, degcnt, N_EDGES);
    scan1_kernel<<<SCAN_NB, 256, 0, stream>>>(degcnt, rowptr, bsums, dinv, N_NODES);
    scan2_kernel<<<1, 256, 0, stream>>>(bsums, SCAN_NB);
    scan3_kernel<<<SCAN_NB, 256, 0, stream>>>(rowptr, bsums, cursor, N_NODES, N_EDGES);
    fill_kernel<IdxT><<<N_EDGES / 256, 256, 0, stream>>>(ei, cursor, csr, N_EDGES);

    // ---- layer 1 ----
    gemm64_kernel<<<(N_NODES / 64) * 2, 256, 0, stream>>>(x, W1, dinv, hbuf);
    gather4_kernel<IdxT><<<(N_NODES * 64) / 256, 256, 0, stream>>>(rowptr, csr, dinv, hbuf, b1, obuf, N_NODES);

    // ---- layer 2 ----
    gemm64_kernel<<<(N_NODES / 64) * 2, 256, 0, stream>>>(obuf, W2, dinv, hbuf);
    gather4_kernel<IdxT><<<(N_NODES * 64) / 256, 256, 0, stream>>>(rowptr, csr, dinv, hbuf, b2, obuf, N_NODES);

    // ---- pool + fc ----
    pool_fc_kernel<<<N_GRAPHS, 128, 0, stream>>>(obuf, batch, Wfc, bfc, out, N_NODES);
}

extern "C" void kernel_launch(void* const* d_in, const int* in_sizes, int n_in,
                              void* d_out, int out_size, void* d_ws, size_t ws_size,
                              hipStream_t stream) {
    const float* x     = (const float*)d_in[0];
    const int*   ei    = (const int*)  d_in[1];
    const int*   batch = (const int*)  d_in[2];
    const float* W1    = (const float*)d_in[3];
    const float* b1    = (const float*)d_in[4];
    const float* W2    = (const float*)d_in[5];
    const float* b2    = (const float*)d_in[6];
    const float* Wfc   = (const float*)d_in[7];
    const float* bfc   = (const float*)d_in[8];
    float* out = (float*)d_out;

    const size_t fbytes = (size_t)N_NODES * NFEAT * sizeof(float);
    const size_t needA = 2 * fbytes + ((size_t)N_EDGES * 4 + 15) / 16 * 16
                       + ((size_t)(N_NODES + 1) * 4 + 15) / 16 * 16
                       + (size_t)N_NODES * 4;
    const size_t needB = 2 * fbytes + ((size_t)N_EDGES * 2 + 15) / 16 * 16
                       + ((size_t)(N_NODES + 1) * 4 + 15) / 16 * 16
                       + (size_t)N_NODES * 4;

    if (ws_size >= needA) {
        run_csr_path<int>(x, ei, batch, W1, b1, W2, b2, Wfc, bfc, out, d_ws, stream);
    } else if (ws_size >= needB) {
        run_csr_path<unsigned short>(x, ei, batch, W1, b1, W2, b2, Wfc, bfc, out, d_ws, stream);
    } else {
        // Tier C: atomic-scatter fallback
        float* ws   = (float*)d_ws;
        int*   degc = (int*)ws;
        float* dinv = ws + N_NODES;
        float* hbuf = ws + 2 * N_NODES;
        float* agg  = hbuf + (size_t)N_NODES * NFEAT;

        hipMemsetAsync(degc, 0, (size_t)N_NODES * sizeof(int), stream);
        edge_deg_int_kernel<<<N_EDGES / 256, 256, 0, stream>>>(ei, degc, N_EDGES);
        dinv_from_int_kernel<<<SCAN_NB, 256, 0, stream>>>(degc, dinv, N_NODES);

        hipMemsetAsync(agg, 0, fbytes, stream);
        gemm64_kernel<<<(N_NODES / 64) * 2, 256, 0, stream>>>(x, W1, dinv, hbuf);
        edge_scatter_kernel<<<(N_EDGES * 32) / 256, 256, 0, stream>>>(ei, dinv, hbuf, agg, N_EDGES);
        post_kernel<<<(N_NODES * 32) / 256, 256, 0, stream>>>(agg, hbuf, dinv, b1, N_NODES);

        gemm64_kernel<<<(N_NODES / 64) * 2, 256, 0, stream>>>(agg, W2, dinv, hbuf);
        hipMemsetAsync(agg, 0, fbytes, stream);
        edge_scatter_kernel<<<(N_EDGES * 32) / 256, 256, 0, stream>>>(ei, dinv, hbuf, agg, N_EDGES);
        post_kernel<<<(N_NODES * 32) / 256, 256, 0, stream>>>(agg, hbuf, dinv, b2, N_NODES);

        pool_fc_kernel<<<N_GRAPHS, 128, 0, stream>>>(agg, batch, Wfc, bfc, out, N_NODES);
    }
}